// Round 13
// baseline (338.378 us; speedup 1.0000x reference)
//
#include <hip/hip_runtime.h>
#include <hip/hip_bf16.h>
#include <stdint.h>

// Problem constants (from reference: N=4264, B=256, NG=8, GS=533, SAMPLE_NUM=10)
#define NN 4264
#define BB 256
#define GSZ 533
#define NGRP 8
#define NSWEEP 10
#define NSTEP (NSWEEP * NGRP)
#define NTOT (BB * GSZ)   // 136448 randoms per step
#define DMAX 48   // exact-table cap (Poisson(15): P(deg>48) ~ 1e-11 per node)
#define DFIX 24   // packed fast-path depth, zero-padded; tail read from exact table
#define NF4 1066  // NN/4 float4s per row (17056 B, 16B-aligned)
#define NIT 17    // ceil(NF4/64) float4-iterations per wave
#define GW (GSZ * DFIX)     // 12792 words = 51168 B per group slab (transposed [k][node])
#define SLABW 12800         // LDS slab words, padded to 50 x 1024 B DMA chunks
#define NCH 50              // 1024-B wave-chunks per pack slab
#define AWRDS 576           // LDS A-slice words (9 x 256 B chunks >= 533 floats)
#define NBBUILD ((NN + 3) / 4)

struct Keys { unsigned k0[NSTEP]; unsigned k1[NSTEP]; };

// ---- threefry2x32, exactly as JAX (20 rounds, key injections every 4) ----
#define TF_ROUND(x0, x1, r) { x0 += x1; x1 = (x1 << (r)) | (x1 >> (32 - (r))); x1 ^= x0; }
#define TF_BODY(K0, K1, C0, C1, O0, O1) {                                   \
  unsigned ks0 = (K0), ks1 = (K1), ks2 = (K0) ^ (K1) ^ 0x1BD11BDAu;          \
  unsigned x0 = (C0) + ks0, x1 = (C1) + ks1;                                 \
  TF_ROUND(x0, x1, 13) TF_ROUND(x0, x1, 15) TF_ROUND(x0, x1, 26) TF_ROUND(x0, x1, 6)  \
  x0 += ks1; x1 += ks2 + 1u;                                                 \
  TF_ROUND(x0, x1, 17) TF_ROUND(x0, x1, 29) TF_ROUND(x0, x1, 16) TF_ROUND(x0, x1, 24) \
  x0 += ks2; x1 += ks0 + 2u;                                                 \
  TF_ROUND(x0, x1, 13) TF_ROUND(x0, x1, 15) TF_ROUND(x0, x1, 26) TF_ROUND(x0, x1, 6)  \
  x0 += ks0; x1 += ks1 + 3u;                                                 \
  TF_ROUND(x0, x1, 17) TF_ROUND(x0, x1, 29) TF_ROUND(x0, x1, 16) TF_ROUND(x0, x1, 24) \
  x0 += ks1; x1 += ks2 + 4u;                                                 \
  TF_ROUND(x0, x1, 13) TF_ROUND(x0, x1, 15) TF_ROUND(x0, x1, 26) TF_ROUND(x0, x1, 6)  \
  x0 += ks2; x1 += ks0 + 5u;                                                 \
  (O0) = x0; (O1) = x1; }

static void tf_host(unsigned k0, unsigned k1, unsigned c0, unsigned c1,
                    unsigned* o0, unsigned* o1) {
  unsigned a, b;
  TF_BODY(k0, k1, c0, c1, a, b);
  *o0 = a; *o1 = b;
}

__device__ __forceinline__ void tf_dev(unsigned k0, unsigned k1, unsigned c0, unsigned c1,
                                       unsigned& o0, unsigned& o1) {
  TF_BODY(k0, k1, c0, c1, o0, o1);
}

// r(step, c) = u*2-1 from the xor-fold of threefry2x32(key_step, (0, c)) — the
// jax.random.uniform (threefry_partitionable) stream. Exact in f32.
__device__ __forceinline__ float tf_r(unsigned k0, unsigned k1, unsigned c) {
  unsigned o0, o1;
  tf_dev(k0, k1, 0u, c, o0, o1);
  const unsigned bits = o0 ^ o1;
  const float u = __uint_as_float((bits >> 9) | 0x3f800000u) - 1.0f;
  return u * 2.0f - 1.0f;
}

// ---- Merged prep: blocks [0, NBBUILD) build tables; the rest fill Atab ----
// Build: pack4[g*GW + k*GSZ + ii] = (bf16_rne(val)<<16) | (col<<2)  TRANSPOSED
//        exact8[p*DMAX + k] = {col, f32 val}; marg[p] = 2^-9*sum|v| + 2e-5
// RNG:   Atab[step*NTOT + c] = atanh(r(step,c)) — sign(tanh(I)-r)==sign(I-A);
//        computed ONCE at full-GPU parallelism (in-loop RNG at 1 block/CU cost
//        ~60 µs across r10/r12 — this is the r8-proven fast path).
__global__ __launch_bounds__(256) void prep(const float* __restrict__ J,
                                            const int* __restrict__ groups,
                                            unsigned* __restrict__ pack4,
                                            float* __restrict__ Atab,
                                            int2* __restrict__ exact8,
                                            int* __restrict__ deg,
                                            float* __restrict__ marg,
                                            Keys keys) {
  if (blockIdx.x >= NBBUILD) {
    const int idx = blockIdx.x - NBBUILD;
    const int step = idx / GSZ;
    const int chunk = idx % GSZ;
    const unsigned c = (unsigned)(chunk * 256 + threadIdx.x);  // < NTOT
    const float r = tf_r(keys.k0[step], keys.k1[step], c);
    Atab[(size_t)step * NTOT + c] = 0.5f * logf((1.0f + r) / (1.0f - r));
    return;
  }
  const int wv = threadIdx.x >> 6, lane = threadIdx.x & 63;
  const int p = blockIdx.x * 4 + wv;
  if (p >= NN) return;
  const int g = p / GSZ;
  const int ii = p - g * GSZ;
  unsigned* pg = pack4 + (size_t)g * GW;
  const int node = groups[p];
  const float4* row = (const float4*)(J + (size_t)node * NN);

  // Phase 1: issue ALL row loads (17 KB/wave in flight -> BW-bound)
  float4 vv[NIT];
#pragma unroll
  for (int it = 0; it < NIT; ++it) {
    const int q = it * 64 + lane;
    vv[it] = (q < NF4) ? row[q] : make_float4(0.0f, 0.0f, 0.0f, 0.0f);
  }

  // Phase 2: ballot compaction on registers (exact ascending-column order)
  int cnt = 0;
  float asum = 0.0f;
#pragma unroll
  for (int it = 0; it < NIT; ++it) {
    const float4 v = vv[it];
    const int c0 = (it * 64 + lane) * 4;
#define COMP(X, CIDX) {                                                        \
      const bool nz = ((X) != 0.0f);                                           \
      const unsigned long long mk = __ballot(nz);                              \
      const int rk = cnt + __popcll(mk & ((1ull << lane) - 1ull));             \
      if (nz) {                                                                \
        if (rk < DFIX) {                                                       \
          const unsigned bits = __float_as_uint(X);                            \
          const unsigned bf = (bits + 0x7fffu + ((bits >> 16) & 1u)) >> 16;    \
          pg[(size_t)rk * GSZ + ii] = (bf << 16) | ((unsigned)(CIDX) << 2);    \
          asum += fabsf(X);                                                    \
        }                                                                      \
        if (rk < DMAX)                                                         \
          exact8[(size_t)p * DMAX + rk] = make_int2((CIDX), __float_as_int(X));\
      }                                                                        \
      cnt += __popcll(mk); }
    COMP(v.x, c0 + 0) COMP(v.y, c0 + 1) COMP(v.z, c0 + 2) COMP(v.w, c0 + 3)
#undef COMP
  }
  for (int k = cnt + lane; k < DFIX; k += 64) pg[(size_t)k * GSZ + ii] = 0u;
  for (int s = 1; s < 64; s <<= 1) asum += __shfl_xor(asum, s, 64);
  if (lane == 0) {
    deg[p] = (cnt > DMAX) ? DMAX : cnt;
    marg[p] = asum * 0.001953125f + 2e-5f;  // 2^-9 * sum|v| + slack
  }
}

// ---- Full Gibbs chain: one workgroup per batch row ----
// 576 threads = 9 waves, one node per thread per group-step. All per-step
// operands arrive by double-buffered async LDS DMA (no VGPR round-trip, no
// register pipelines to spill): 51 KB pack slab for group g+1 + 2.3 KB
// A-threshold slice for step s+1, both issued at step top and drained by the
// compiler's vmcnt(0) before barrier1. Step-top work after the gather is a
// SINGLE SUBTRACT (sign(I - atanh(r))). USE_A=false: r5-proven in-loop path
// (only if ws_size is too small for Atab).
template <bool USE_A>
__global__ __launch_bounds__(576, 3) void gibbs(const float* __restrict__ m0,
                                                const float* __restrict__ H,
                                                const int* __restrict__ groups,
                                                const unsigned* __restrict__ pack4,
                                                const float* __restrict__ Atab,
                                                const int2* __restrict__ exact8,
                                                const int* __restrict__ deg,
                                                const float* __restrict__ marg,
                                                float* __restrict__ out,
                                                Keys keys) {
  __shared__ float m_lds[NN];
  __shared__ unsigned pbuf[2][SLABW];
  __shared__ float abuf[2][AWRDS];
  const int b = blockIdx.x;
  const int i = threadIdx.x;
  const int wv = i >> 6, lane = i & 63;
  const bool active = (i < GSZ);

  for (int n = i; n < NN; n += 576) m_lds[n] = m0[(size_t)b * NN + n];

#define STAGE(GN, BUF) {                                                        \
    const char* gbase = (const char*)pack4 + (size_t)(GN) * (GW * 4);           \
    char* lbase = (char*)(&pbuf[(BUF)][0]);                                     \
    for (int ch = wv; ch < NCH; ch += 9) {                                      \
      __builtin_amdgcn_global_load_lds(                                         \
          (const __attribute__((address_space(1))) unsigned*)(gbase + ch * 1024 + lane * 16), \
          (__attribute__((address_space(3))) unsigned*)(lbase + ch * 1024 + lane * 16),       \
          16, 0, 0);                                                            \
    }                                                                           \
  }
// A slice for step SN: 2132 B at Atab + (SN*NTOT + b*GSZ)*4 (4B-aligned only),
// staged as 9 size-4 chunks (one per wave). Overread ~172 B is harmless
// (Atab is not last in the workspace).
#define STAGE_A(SN, BUF) if (USE_A) {                                           \
    const char* gA = (const char*)Atab + ((size_t)(SN) * NTOT + (size_t)b * GSZ) * 4; \
    char* lA = (char*)(&abuf[(BUF)][0]);                                        \
    if (wv < 9) {                                                               \
      __builtin_amdgcn_global_load_lds(                                         \
          (const __attribute__((address_space(1))) unsigned*)(gA + wv * 256 + lane * 4),  \
          (__attribute__((address_space(3))) unsigned*)(lA + wv * 256 + lane * 4),        \
          4, 0, 0);                                                             \
    }                                                                           \
  }

  STAGE(0, 0)
  STAGE_A(0, 0)

  // Per-thread per-group preload (step-invariant).
  int nodeg[NGRP];
  float hg[NGRP], mgg[NGRP];
  int dgg[NGRP];
  if (active) {
#pragma unroll
    for (int g = 0; g < NGRP; ++g) {
      const int p = g * GSZ + i;
      nodeg[g] = groups[p];
      hg[g] = H[nodeg[g]];
      dgg[g] = deg[p];
      mgg[g] = marg[p];
    }
  }
  const unsigned c = (unsigned)(b * GSZ + i);
  __syncthreads();  // m_lds init + step-0 DMA complete

#pragma unroll 1
  for (int t = 0; t < NSWEEP; ++t) {
#pragma unroll
    for (int g = 0; g < NGRP; ++g) {
      const int step = t * NGRP + g;
      const int cur = step & 1;
      // Kick off next step's DMA first (into the other buffers; no reader yet).
      STAGE((g + 1) & (NGRP - 1), cur ^ 1)
      {
        const int sn = (step + 1 < NSTEP) ? step + 1 : step;
        STAGE_A(sn, cur ^ 1)
      }

      float nv = 0.0f;
      if (active) {
        // Gather-sum; pack words lane-consecutive in LDS (conflict-free).
        const unsigned* pb = pbuf[cur];
        float a0 = 0.0f, a1 = 0.0f, a2 = 0.0f, a3 = 0.0f;
        // value = high-16 bits as f32 (bf16<<16); addr = low-16 = byte offset
#define MV(W)  (*(const float*)((const char*)m_lds + ((W) & 0xFFFCu)))
#pragma unroll
        for (int k = 0; k < DFIX; k += 4) {
          const unsigned e0 = pb[(k + 0) * GSZ + i];
          const unsigned e1 = pb[(k + 1) * GSZ + i];
          const unsigned e2 = pb[(k + 2) * GSZ + i];
          const unsigned e3 = pb[(k + 3) * GSZ + i];
          a0 += __uint_as_float(e0 & 0xFFFF0000u) * MV(e0);
          a1 += __uint_as_float(e1 & 0xFFFF0000u) * MV(e1);
          a2 += __uint_as_float(e2 & 0xFFFF0000u) * MV(e2);
          a3 += __uint_as_float(e3 & 0xFFFF0000u) * MV(e3);
        }
#undef MV
        const int dg = dgg[g];
        if (__builtin_expect(dg > DFIX, 0)) {
          const int2* ep = exact8 + (size_t)(g * GSZ + i) * DMAX;
          for (int k = DFIX; k < dg; ++k) {
            const int2 e = ep[k];
            a0 += __int_as_float(e.y) * m_lds[e.x];
          }
        }
        const float I = ((a0 + a1) + (a2 + a3)) + hg[g];

        float d;
        if (USE_A) {
          d = I - abuf[cur][i];   // single subtract: sign(I - atanh(r))
        } else {
          d = tanhf(I) - tf_r(keys.k0[step], keys.k1[step], c);
        }
        if (__builtin_expect(fabsf(d) > mgg[g], 1)) {
          nv = (d > 0.0f) ? 1.0f : -1.0f;
        } else {
          // Boundary-close (~0.3% of wave-steps): settle in f64 from the
          // exact f32 table (ascending col), recomputing r exactly.
          const float r = tf_r(keys.k0[step], keys.k1[step], c);
          const int2* ep = exact8 + (size_t)(g * GSZ + i) * DMAX;
          double I64 = (double)hg[g];
          for (int k = 0; k < dg; ++k) {
            const int2 e = ep[k];
            I64 += (double)__int_as_float(e.y) * (double)m_lds[e.x];
          }
          const double diff = tanh(I64) - (double)r;
          nv = (diff > 0.0) ? 1.0f : ((diff < 0.0) ? -1.0f : 0.0f);
        }
      }
      __syncthreads();                  // gathers done + next-step DMA drained
      if (active) m_lds[nodeg[g]] = nv; // compute-all-then-set semantics
      __syncthreads();                  // scatter visible before next group
    }
  }

  for (int n = i; n < NN; n += 576) out[(size_t)b * NN + n] = m_lds[n];
#undef STAGE
#undef STAGE_A
}

extern "C" void kernel_launch(void* const* d_in, const int* in_sizes, int n_in,
                              void* d_out, int out_size, void* d_ws, size_t ws_size,
                              hipStream_t stream) {
  const float* m0     = (const float*)d_in[0];
  const float* J      = (const float*)d_in[1];
  const float* H      = (const float*)d_in[2];
  const int*   groups = (const int*)d_in[3];
  // d_in[4] = sample_num (=10, hardcoded as NSWEEP)

  // Workspace: pack4[NGRP*GW] u32 (409 KB) +64 pad | Atab[NSTEP*NTOT] f32
  //            (43.7 MB) | exact8[NN*DMAX] int2 (1.64 MB) | deg | marg
  //            -> ~45.8 MB (same footprint r7/r8 proved fits)
  char* ws = (char*)d_ws;
  unsigned* pack4  = (unsigned*)ws;                     ws += (size_t)NGRP * GW * 4 + 64;
  float*    Atab   = (float*)ws;                        ws += (size_t)NSTEP * NTOT * 4;
  int2*     exact8 = (int2*)ws;                         ws += (size_t)NN * DMAX * 8;
  int*      deg    = (int*)ws;                          ws += (size_t)NN * 4;
  float*    marg   = (float*)ws;                        ws += (size_t)NN * 4;
  const bool use_a = ((size_t)(ws - (char*)d_ws) <= ws_size);  // fixed -> graph-safe

  // Host-side key schedule, jax_threefry_partitionable=True (fold-like split):
  // key(42) -> (0, 42); split(key, n)[i] = threefry2x32(key, (0, i)).
  Keys keys;
  for (int t = 0; t < NSWEEP; ++t) {
    unsigned ik0, ik1;
    tf_host(0u, 42u, 0u, (unsigned)t, &ik0, &ik1);
    for (int g = 0; g < NGRP; ++g) {
      unsigned gk0, gk1;
      tf_host(ik0, ik1, 0u, (unsigned)g, &gk0, &gk1);
      keys.k0[t * NGRP + g] = gk0;
      keys.k1[t * NGRP + g] = gk1;
    }
  }

  if (use_a) {
    prep<<<NBBUILD + NSTEP * GSZ, 256, 0, stream>>>(J, groups, pack4, Atab,
                                                    exact8, deg, marg, keys);
    gibbs<true><<<BB, 576, 0, stream>>>(m0, H, groups, pack4, Atab, exact8,
                                        deg, marg, (float*)d_out, keys);
  } else {
    prep<<<NBBUILD, 256, 0, stream>>>(J, groups, pack4, Atab,
                                      exact8, deg, marg, keys);
    gibbs<false><<<BB, 576, 0, stream>>>(m0, H, groups, pack4, Atab, exact8,
                                         deg, marg, (float*)d_out, keys);
  }
}

// Round 14
// 275.178 us; speedup vs baseline: 1.2297x; 1.2297x over previous
//
#include <hip/hip_runtime.h>
#include <hip/hip_bf16.h>
#include <stdint.h>

// Problem constants (from reference: N=4264, B=256, NG=8, GS=533, SAMPLE_NUM=10)
#define NN 4264
#define BB 256
#define GSZ 533
#define NGRP 8
#define NSWEEP 10
#define NSTEP (NSWEEP * NGRP)
#define DMAX 48   // exact-table cap (Poisson(15): P(deg>48) ~ 1e-11 per node)
#define DFIX 24   // packed fast-path depth, zero-padded; tail read from exact table
#define NF4 1066  // NN/4 float4s per row (17056 B, 16B-aligned)
#define NIT 17    // ceil(NF4/64) float4-iterations per wave

struct Keys { unsigned k0[NSTEP]; unsigned k1[NSTEP]; };

// ---- threefry2x32, exactly as JAX (20 rounds, key injections every 4) ----
#define TF_ROUND(x0, x1, r) { x0 += x1; x1 = (x1 << (r)) | (x1 >> (32 - (r))); x1 ^= x0; }
#define TF_BODY(K0, K1, C0, C1, O0, O1) {                                   \
  unsigned ks0 = (K0), ks1 = (K1), ks2 = (K0) ^ (K1) ^ 0x1BD11BDAu;          \
  unsigned x0 = (C0) + ks0, x1 = (C1) + ks1;                                 \
  TF_ROUND(x0, x1, 13) TF_ROUND(x0, x1, 15) TF_ROUND(x0, x1, 26) TF_ROUND(x0, x1, 6)  \
  x0 += ks1; x1 += ks2 + 1u;                                                 \
  TF_ROUND(x0, x1, 17) TF_ROUND(x0, x1, 29) TF_ROUND(x0, x1, 16) TF_ROUND(x0, x1, 24) \
  x0 += ks2; x1 += ks0 + 2u;                                                 \
  TF_ROUND(x0, x1, 13) TF_ROUND(x0, x1, 15) TF_ROUND(x0, x1, 26) TF_ROUND(x0, x1, 6)  \
  x0 += ks0; x1 += ks1 + 3u;                                                 \
  TF_ROUND(x0, x1, 17) TF_ROUND(x0, x1, 29) TF_ROUND(x0, x1, 16) TF_ROUND(x0, x1, 24) \
  x0 += ks1; x1 += ks2 + 4u;                                                 \
  TF_ROUND(x0, x1, 13) TF_ROUND(x0, x1, 15) TF_ROUND(x0, x1, 26) TF_ROUND(x0, x1, 6)  \
  x0 += ks2; x1 += ks0 + 5u;                                                 \
  (O0) = x0; (O1) = x1; }

static void tf_host(unsigned k0, unsigned k1, unsigned c0, unsigned c1,
                    unsigned* o0, unsigned* o1) {
  unsigned a, b;
  TF_BODY(k0, k1, c0, c1, a, b);
  *o0 = a; *o1 = b;
}

__device__ __forceinline__ void tf_dev(unsigned k0, unsigned k1, unsigned c0, unsigned c1,
                                       unsigned& o0, unsigned& o1) {
  TF_BODY(k0, k1, c0, c1, o0, o1);
}

// r(step, c) = u*2-1 from the xor-fold of threefry2x32(key_step, (0, c)) — the
// jax.random.uniform (threefry_partitionable) stream. Exact in f32.
__device__ __forceinline__ float tf_r(unsigned k0, unsigned k1, unsigned c) {
  unsigned o0, o1;
  tf_dev(k0, k1, 0u, c, o0, o1);
  const unsigned bits = o0 ^ o1;
  const float u = __uint_as_float((bits >> 9) | 0x3f800000u) - 1.0f;
  return u * 2.0f - 1.0f;
}

// ---- Build tables: wave-per-row, full-row register prefetch, no barriers ----
// Row p = g*GSZ + i -> node = groups[p].
// pack4[p*DFIX + k]  = (bf16_rne(val) << 16) | (col << 2)   (zero-padded;
//                      low half is the LDS *byte* offset of m[col])
// exact8[p*DMAX + k] = {col, f32 val}                       (ascending col)
// marg[p] = 2^-9 * sum_{k<DFIX} |val| + 2e-5                (screen margin;
//           covers bf16 + f32-sum + f32 atanh/log error ~3e-6 — r8/r11-proven)
__global__ __launch_bounds__(256) void build_ell(const float* __restrict__ J,
                                                 const int* __restrict__ groups,
                                                 unsigned* __restrict__ pack4,
                                                 int2* __restrict__ exact8,
                                                 int* __restrict__ deg,
                                                 float* __restrict__ marg) {
  const int wv = threadIdx.x >> 6, lane = threadIdx.x & 63;
  const int p = blockIdx.x * 4 + wv;
  if (p >= NN) return;
  const int node = groups[p];
  const float4* row = (const float4*)(J + (size_t)node * NN);

  // Phase 1: issue ALL row loads (17 KB/wave in flight -> BW-bound, not latency)
  float4 vv[NIT];
#pragma unroll
  for (int it = 0; it < NIT; ++it) {
    const int q = it * 64 + lane;
    vv[it] = (q < NF4) ? row[q] : make_float4(0.0f, 0.0f, 0.0f, 0.0f);
  }

  // Phase 2: ballot compaction on registers (exact ascending-column order)
  int cnt = 0;
  float asum = 0.0f;
#pragma unroll
  for (int it = 0; it < NIT; ++it) {
    const float4 v = vv[it];
    const int c0 = (it * 64 + lane) * 4;
#define COMP(X, CIDX) {                                                        \
      const bool nz = ((X) != 0.0f);                                           \
      const unsigned long long mk = __ballot(nz);                              \
      const int rk = cnt + __popcll(mk & ((1ull << lane) - 1ull));             \
      if (nz) {                                                                \
        if (rk < DFIX) {                                                       \
          const unsigned bits = __float_as_uint(X);                            \
          const unsigned bf = (bits + 0x7fffu + ((bits >> 16) & 1u)) >> 16;    \
          pack4[(size_t)p * DFIX + rk] = (bf << 16) | ((unsigned)(CIDX) << 2); \
          asum += fabsf(X);                                                    \
        }                                                                      \
        if (rk < DMAX)                                                         \
          exact8[(size_t)p * DMAX + rk] = make_int2((CIDX), __float_as_int(X));\
      }                                                                        \
      cnt += __popcll(mk); }
    COMP(v.x, c0 + 0) COMP(v.y, c0 + 1) COMP(v.z, c0 + 2) COMP(v.w, c0 + 3)
#undef COMP
  }
  for (int k = cnt + lane; k < DFIX; k += 64) pack4[(size_t)p * DFIX + k] = 0u;
  for (int s = 1; s < 64; s <<= 1) asum += __shfl_xor(asum, s, 64);
  if (lane == 0) {
    deg[p] = (cnt > DMAX) ? DMAX : cnt;
    marg[p] = asum * 0.001953125f + 2e-5f;  // 2^-9 * sum|v| + slack
  }
}

// ---- Full Gibbs chain: one workgroup per batch row (rows are independent) ----
// 576 threads = 9 waves, one node per thread per group-step.
// The proven-best combination (config matrix r8/r10/r11/r13):
//  - pack words: REGISTER staging at DFIX 24 (r10's layout — LDS-DMA lost by
//    ~60 µs in r12/r13; DFIX 32 spilled in r11)
//  - decision: SINGLE SUBTRACT sign(I - atanh(r)) with atanh computed IN-LOOP
//    one step ahead (r8 proved removing tanhf from the gather->compare path is
//    worth 16 µs; doing atanh here instead of an Atab kernel saves r8's ~25 µs
//    prep + 44 MB HBM pollution)
__global__ __launch_bounds__(576, 3) void gibbs(const float* __restrict__ m0,
                                                const float* __restrict__ H,
                                                const int* __restrict__ groups,
                                                const unsigned* __restrict__ pack4,
                                                const int2* __restrict__ exact8,
                                                const int* __restrict__ deg,
                                                const float* __restrict__ marg,
                                                float* __restrict__ out,
                                                Keys keys) {
  __shared__ float m_lds[NN];
  const int b = blockIdx.x;
  const int i = threadIdx.x;
  const bool active = (i < GSZ);

  for (int n = i; n < NN; n += 576) m_lds[n] = m0[(size_t)b * NN + n];

  // Per-thread per-group preload (step-invariant).
  int nodeg[NGRP];
  float hg[NGRP], mgg[NGRP];
  int dgg[NGRP];
  if (active) {
#pragma unroll
    for (int g = 0; g < NGRP; ++g) {
      const int p = g * GSZ + i;
      nodeg[g] = groups[p];
      hg[g] = H[nodeg[g]];
      dgg[g] = deg[p];
      mgg[g] = marg[p];
    }
  }

  const unsigned c = (unsigned)(b * GSZ + i);

  // Prime both pipelines: group-0 pack words + step-0 threshold.
  uint4 w0, w1, w2, w3, w4, w5;
  float rcur = 0.0f, Acur = 0.0f;
  if (active) {
    const uint4* q = (const uint4*)(pack4 + (size_t)i * DFIX);
    w0 = q[0]; w1 = q[1]; w2 = q[2]; w3 = q[3]; w4 = q[4]; w5 = q[5];
    rcur = tf_r(keys.k0[0], keys.k1[0], c);
    Acur = 0.5f * logf((1.0f + rcur) / (1.0f - rcur));  // -inf at r=-1 -> +1, correct
  }
  __syncthreads();

#pragma unroll 1
  for (int t = 0; t < NSWEEP; ++t) {
#pragma unroll
    for (int g = 0; g < NGRP; ++g) {
      const int step = t * NGRP + g;
      float nv = 0.0f;
      float rnext = 0.0f, Anext = 0.0f;
      uint4 n0, n1, n2, n3, n4, n5;
      if (active) {
        // Prefetch next group-step's pack words (independent of barriers).
        {
          const int gn = (g + 1) & (NGRP - 1);
          const uint4* qn = (const uint4*)(pack4 + (size_t)(gn * GSZ + i) * DFIX);
          n0 = qn[0]; n1 = qn[1]; n2 = qn[2]; n3 = qn[3]; n4 = qn[4]; n5 = qn[5];
        }
        // Next step's threefry + atanh: the long dependent chains retire in
        // the gather/barrier shadow, consumed only next iteration.
        {
          const int sn = (step + 1 < NSTEP) ? step + 1 : step;
          rnext = tf_r(keys.k0[sn], keys.k1[sn], c);
          Anext = 0.5f * logf((1.0f + rnext) / (1.0f - rnext));
        }

        // Gather-sum from current registers.
        float a0 = 0.0f, a1 = 0.0f, a2 = 0.0f, a3 = 0.0f;
        // value = high-16 bits as f32 (bf16<<16); addr = low-16 = byte offset
        // (padded entries read m_lds[0] * 0 -> broadcast, conflict-free)
#define MV(W)  (*(const float*)((const char*)m_lds + ((W) & 0xFFFCu)))
#define ACC(W) \
        a0 += __uint_as_float((W).x & 0xFFFF0000u) * MV((W).x); \
        a1 += __uint_as_float((W).y & 0xFFFF0000u) * MV((W).y); \
        a2 += __uint_as_float((W).z & 0xFFFF0000u) * MV((W).z); \
        a3 += __uint_as_float((W).w & 0xFFFF0000u) * MV((W).w);
        ACC(w0) ACC(w1) ACC(w2) ACC(w3) ACC(w4) ACC(w5)
#undef ACC
#undef MV
        const int dg = dgg[g];
        if (__builtin_expect(dg > DFIX, 0)) {
          const int2* ep = exact8 + (size_t)(g * GSZ + i) * DMAX;
          for (int k = DFIX; k < dg; ++k) {
            const int2 e = ep[k];
            a0 += __int_as_float(e.y) * m_lds[e.x];
          }
        }
        const float I = ((a0 + a1) + (a2 + a3)) + hg[g];

        // Decision: one subtract. sign(I - atanh(r)) == sign(tanh(I) - r).
        const float d = I - Acur;
        if (__builtin_expect(fabsf(d) > mgg[g], 1)) {
          nv = (d > 0.0f) ? 1.0f : -1.0f;
        } else {
          // Boundary-close: settle in f64 from exact f32 table (ascending col).
          const int2* ep = exact8 + (size_t)(g * GSZ + i) * DMAX;
          double I64 = (double)hg[g];
          for (int k = 0; k < dg; ++k) {
            const int2 e = ep[k];
            I64 += (double)__int_as_float(e.y) * (double)m_lds[e.x];
          }
          const double diff = tanh(I64) - (double)rcur;
          nv = (diff > 0.0) ? 1.0f : ((diff < 0.0) ? -1.0f : 0.0f);
        }
      }
      __syncthreads();                  // all gathers done
      if (active) m_lds[nodeg[g]] = nv; // compute-all-then-set semantics
      __syncthreads();                  // scatter visible before next group
      w0 = n0; w1 = n1; w2 = n2; w3 = n3; w4 = n4; w5 = n5;
      rcur = rnext; Acur = Anext;
    }
  }

  for (int n = i; n < NN; n += 576) out[(size_t)b * NN + n] = m_lds[n];
}

extern "C" void kernel_launch(void* const* d_in, const int* in_sizes, int n_in,
                              void* d_out, int out_size, void* d_ws, size_t ws_size,
                              hipStream_t stream) {
  const float* m0     = (const float*)d_in[0];
  const float* J      = (const float*)d_in[1];
  const float* H      = (const float*)d_in[2];
  const int*   groups = (const int*)d_in[3];
  // d_in[4] = sample_num (=10, hardcoded as NSWEEP)

  // Workspace: pack4[NN*DFIX] u32 (409 KB) | exact8[NN*DMAX] int2 (1.64 MB)
  //          | deg[NN] i32 | marg[NN] f32   -> ~2.08 MB total
  char* ws = (char*)d_ws;
  unsigned* pack4  = (unsigned*)ws;                     ws += (size_t)NN * DFIX * 4;
  int2*     exact8 = (int2*)ws;                         ws += (size_t)NN * DMAX * 8;
  int*      deg    = (int*)ws;                          ws += (size_t)NN * 4;
  float*    marg   = (float*)ws;

  // Host-side key schedule, jax_threefry_partitionable=True (fold-like split):
  // key(42) -> (0, 42); split(key, n)[i] = threefry2x32(key, (0, i)).
  Keys keys;
  for (int t = 0; t < NSWEEP; ++t) {
    unsigned ik0, ik1;
    tf_host(0u, 42u, 0u, (unsigned)t, &ik0, &ik1);
    for (int g = 0; g < NGRP; ++g) {
      unsigned gk0, gk1;
      tf_host(ik0, ik1, 0u, (unsigned)g, &gk0, &gk1);
      keys.k0[t * NGRP + g] = gk0;
      keys.k1[t * NGRP + g] = gk1;
    }
  }

  build_ell<<<(NN + 3) / 4, 256, 0, stream>>>(J, groups, pack4, exact8, deg, marg);
  gibbs<<<BB, 576, 0, stream>>>(m0, H, groups, pack4, exact8, deg, marg,
                                (float*)d_out, keys);
}